// Round 1
// 111.014 us; speedup vs baseline: 1.0242x; 1.0242x over previous
//
#include <hip/hip_runtime.h>

// UVCrossAttention — MI355X (gfx950), Round 4: bf16 MFMA for the GEMM phases.
//
// Algebra (unchanged): dotv[q,v] = (key@W_v^T)[q]·value[v] + key[q]·b_v.
// New structure:
//   D1: transpose W_off,W_attn -> [n][k] fp32 in ws; keyp = key@W_v^T via the
//       proven fp32 tile GEMM (small); c[q] = key[q]·b_v.
//   D2: ONE uniform NT MFMA GEMM (A[m][128] fp32, B[n][128] fp32 -> C fp32):
//       off  = query @ WoffT^T  + b_off   (64 tiles of 128x128)
//       aw   = query @ WattnT^T + b_attn  (32 tiles)
//       dotv = keyp  @ value^T  + c[m]    (64 tiles)
//       Staging converts fp32->bf16(RNE) into XOR-swizzled LDS; compute is
//       v_mfma_f32_16x16x32_bf16 with fp32 accumulation. A/B fragments use
//       the SAME k-slot mapping (both row-major [row][k]), so correctness is
//       invariant to the HW's internal k ordering; C/D layout is the
//       HW-verified col=lane&15, row=(lane>>4)*4+reg.
//   D3: sampler + fused @W_o + residual — byte-identical to the passing R3.

#define NQ   1024
#define NV   1024
#define ND   128
#define NP   4
#define IMG_W 32
#define IMG_H 32

typedef __attribute__((ext_vector_type(8))) short bfx8;
typedef __attribute__((ext_vector_type(4))) float f32x4;

__device__ __forceinline__ unsigned short bf_rne(float f) {
  unsigned u = __float_as_uint(f);
  return (unsigned short)((u + 0x7FFFu + ((u >> 16) & 1u)) >> 16);
}

// ---------------------------------------------------------------------------
// fp32 64x64 tile GEMM (proven in R3) — used only for keyp in D1.
// ---------------------------------------------------------------------------
__device__ __forceinline__ void gemm_tile64(
    const float* __restrict__ A, const float* __restrict__ B,
    int N, bool nt,
    const float* __restrict__ bias, const float* __restrict__ cvec,
    float* __restrict__ C, int m0, int n0, float* sA, float* sB) {
  const int tid = threadIdx.x;
#pragma unroll
  for (int k = 0; k < 8; ++k) {
    int c = tid + k * 256;
    int m = c & 63, e4 = c >> 6;
    const float4 v = *(const float4*)(A + (size_t)(m0 + m) * 128 + e4 * 4);
    sA[(e4 * 4 + 0) * 64 + m] = v.x;
    sA[(e4 * 4 + 1) * 64 + m] = v.y;
    sA[(e4 * 4 + 2) * 64 + m] = v.z;
    sA[(e4 * 4 + 3) * 64 + m] = v.w;
  }
  if (nt) {
#pragma unroll
    for (int k = 0; k < 8; ++k) {
      int c = tid + k * 256;
      int n = c & 63, e4 = c >> 6;
      const float4 v = *(const float4*)(B + (size_t)(n0 + n) * 128 + e4 * 4);
      sB[(e4 * 4 + 0) * 64 + n] = v.x;
      sB[(e4 * 4 + 1) * 64 + n] = v.y;
      sB[(e4 * 4 + 2) * 64 + n] = v.z;
      sB[(e4 * 4 + 3) * 64 + n] = v.w;
    }
  } else {
#pragma unroll
    for (int k = 0; k < 8; ++k) {
      int c = tid + k * 256;
      int n4 = c & 15, e = c >> 4;
      *(float4*)(sB + e * 64 + n4 * 4) =
          *(const float4*)(B + (size_t)e * N + n0 + n4 * 4);
    }
  }
  __syncthreads();

  const int tx = tid & 15, ty = tid >> 4;
  float acc[4][4] = {};
#pragma unroll 8
  for (int e = 0; e < 128; ++e) {
    const float4 a = *(const float4*)(sA + e * 64 + ty * 4);
    const float4 b = *(const float4*)(sB + e * 64 + tx * 4);
    acc[0][0] += a.x * b.x; acc[0][1] += a.x * b.y; acc[0][2] += a.x * b.z; acc[0][3] += a.x * b.w;
    acc[1][0] += a.y * b.x; acc[1][1] += a.y * b.y; acc[1][2] += a.y * b.z; acc[1][3] += a.y * b.w;
    acc[2][0] += a.z * b.x; acc[2][1] += a.z * b.y; acc[2][2] += a.z * b.z; acc[2][3] += a.z * b.w;
    acc[3][0] += a.w * b.x; acc[3][1] += a.w * b.y; acc[3][2] += a.w * b.z; acc[3][3] += a.w * b.w;
  }

  float4 bv = make_float4(0.f, 0.f, 0.f, 0.f);
  if (bias) bv = *(const float4*)(bias + n0 + tx * 4);
#pragma unroll
  for (int i = 0; i < 4; ++i) {
    const int m = m0 + ty * 4 + i;
    float cv = cvec ? cvec[m] : 0.f;
    float4 r;
    r.x = acc[i][0] + bv.x + cv;
    r.y = acc[i][1] + bv.y + cv;
    r.z = acc[i][2] + bv.z + cv;
    r.w = acc[i][3] + bv.w + cv;
    *(float4*)(C + (size_t)m * 128 + n0 + tx * 4) = r;  // keyp ldc == 128
  }
}

// ---------------------------------------------------------------------------
// D1 helpers: 64-col transpose Wsrc[128][N] -> dst[n][128] (fp32).
// ---------------------------------------------------------------------------
__device__ __forceinline__ void transpose64(const float* __restrict__ src, int N,
                                            int n0, float* __restrict__ dst,
                                            float* lds) {
  const int tid = threadIdx.x;
#pragma unroll
  for (int it = 0; it < 8; ++it) {
    int c = tid + it * 256;          // 2048 chunks = 128 k-rows x 16 float4
    int k = c >> 4, cf = c & 15;
    float4 v = *(const float4*)(src + (size_t)k * N + n0 + cf * 4);
    lds[k * 65 + cf * 4 + 0] = v.x;
    lds[k * 65 + cf * 4 + 1] = v.y;
    lds[k * 65 + cf * 4 + 2] = v.z;
    lds[k * 65 + cf * 4 + 3] = v.w;
  }
  __syncthreads();
#pragma unroll
  for (int it = 0; it < 8; ++it) {
    int c = tid + it * 256;          // 2048 chunks = 64 n-rows x 32 float4
    int dn = c >> 5, kq = c & 31;
    float4 v;
    v.x = lds[(kq * 4 + 0) * 65 + dn];
    v.y = lds[(kq * 4 + 1) * 65 + dn];
    v.z = lds[(kq * 4 + 2) * 65 + dn];
    v.w = lds[(kq * 4 + 3) * 65 + dn];
    *(float4*)(dst + (size_t)(n0 + dn) * 128 + kq * 4) = v;
  }
}

__global__ __launch_bounds__(256, 2) void d1_kernel(
    const float* __restrict__ key, const float* __restrict__ W_v,
    const float* __restrict__ b_v, const float* __restrict__ W_off,
    const float* __restrict__ W_attn,
    float* __restrict__ keyp_ws, float* __restrict__ c_ws,
    float* __restrict__ wofft, float* __restrict__ wattnt) {
  __shared__ float smem[16384];      // 64 KB, shared by all branches
  const int t = blockIdx.x;
  if (t < 16) {
    transpose64(W_off, 1024, t * 64, wofft, smem);
  } else if (t < 24) {
    transpose64(W_attn, 512, (t - 16) * 64, wattnt, smem);
  } else if (t < 56) {
    const int u = t - 24;            // 32 tiles: 16 m x 2 n, keyp = key@W_v^T
    gemm_tile64(key, W_v, 128, true, nullptr, nullptr, keyp_ws,
                (u >> 1) * 64, (u & 1) * 64, smem, smem + 8192);
  } else {
    for (int i = 0; i < 4; ++i) {    // c[q] = key[q]·b_v (b_v==0 here)
      const int q = threadIdx.x + i * 256;
      float s = 0.f;
      for (int e = 0; e < 128; ++e) s += key[(size_t)q * 128 + e] * b_v[e];
      c_ws[q] = s;
    }
  }
}

// ---------------------------------------------------------------------------
// D2: uniform NT bf16-MFMA GEMM. 128x128 tile, 256 thr = 4 waves (2x2),
// each wave 64x64 = 4x4 fragments of 16x16, K=128 in 4 steps of 32.
// LDS: A,B tiles as bf16 with XOR swizzle (byte ^= (row&15)<<4).
// ---------------------------------------------------------------------------
__device__ __forceinline__ void mfma_tile128(
    const float* __restrict__ A,      // [M][128] fp32
    const float* __restrict__ B,      // [N][128] fp32 (row-major n,k)
    const float* __restrict__ bias,   // [N] or null
    const float* __restrict__ cvec,   // [M] or null
    float* __restrict__ C, int ldc,
    int m0, int n0, unsigned short* sA, unsigned short* sB) {
  const int tid = threadIdx.x;

  // stage 128 rows x 128 k, fp32 -> bf16 RNE, 16B chunks, swizzled.
  {
    const float* srcs[2] = {A, B};
    const int r0s[2] = {m0, n0};
    unsigned short* dsts[2] = {sA, sB};
#pragma unroll
    for (int s = 0; s < 2; ++s) {
      const float* src = srcs[s];
      const int r0 = r0s[s];
      unsigned short* dst = dsts[s];
#pragma unroll
      for (int it = 0; it < 8; ++it) {
        int c = tid + it * 256;        // 2048 chunks = 128 rows x 16
        int r = c >> 4, cc = c & 15;
        const float* p = src + (size_t)(r0 + r) * 128 + cc * 8;
        float4 f0 = *(const float4*)p;
        float4 f1 = *(const float4*)(p + 4);
        bfx8 v;
        v[0] = (short)bf_rne(f0.x); v[1] = (short)bf_rne(f0.y);
        v[2] = (short)bf_rne(f0.z); v[3] = (short)bf_rne(f0.w);
        v[4] = (short)bf_rne(f1.x); v[5] = (short)bf_rne(f1.y);
        v[6] = (short)bf_rne(f1.z); v[7] = (short)bf_rne(f1.w);
        int byte = r * 256 + ((cc * 16) ^ ((r & 15) << 4));
        *(bfx8*)((char*)dst + byte) = v;
      }
    }
  }
  __syncthreads();

  const int l = tid & 63;
  const int w = tid >> 6;
  const int wr = w >> 1, wc = w & 1;   // 2x2 wave grid over the 128x128 tile
  const int lr = l & 15, g = l >> 4;   // fragment row/col = lr, k-group = g

  f32x4 acc[4][4];
#pragma unroll
  for (int mi = 0; mi < 4; ++mi)
#pragma unroll
    for (int ni = 0; ni < 4; ++ni) {
      f32x4 z = {0.f, 0.f, 0.f, 0.f};
      acc[mi][ni] = z;
    }

#pragma unroll
  for (int ks = 0; ks < 4; ++ks) {
    const int colb = (ks * 64 + g * 16) ^ (lr << 4);  // (row&15)==lr for all frags
    bfx8 af[4], bfr[4];
#pragma unroll
    for (int mi = 0; mi < 4; ++mi) {
      int r = wr * 64 + mi * 16 + lr;
      af[mi] = *(const bfx8*)((const char*)sA + r * 256 + colb);
    }
#pragma unroll
    for (int ni = 0; ni < 4; ++ni) {
      int r = wc * 64 + ni * 16 + lr;
      bfr[ni] = *(const bfx8*)((const char*)sB + r * 256 + colb);
    }
#pragma unroll
    for (int mi = 0; mi < 4; ++mi)
#pragma unroll
      for (int ni = 0; ni < 4; ++ni)
        acc[mi][ni] = __builtin_amdgcn_mfma_f32_16x16x32_bf16(
            af[mi], bfr[ni], acc[mi][ni], 0, 0, 0);
  }

  // epilogue: C/D layout col=lane&15, row=(lane>>4)*4+reg (HW-verified)
#pragma unroll
  for (int mi = 0; mi < 4; ++mi) {
    float cv[4];
#pragma unroll
    for (int i = 0; i < 4; ++i) {
      int row = m0 + wr * 64 + mi * 16 + g * 4 + i;
      cv[i] = cvec ? cvec[row] : 0.f;
    }
#pragma unroll
    for (int ni = 0; ni < 4; ++ni) {
      int col = n0 + wc * 64 + ni * 16 + lr;
      float bn = bias ? bias[col] : 0.f;
#pragma unroll
      for (int i = 0; i < 4; ++i) {
        int row = m0 + wr * 64 + mi * 16 + g * 4 + i;
        C[(size_t)row * ldc + col] = acc[mi][ni][i] + bn + cv[i];
      }
    }
  }
}

__global__ __launch_bounds__(256, 2) void d2_kernel(
    const float* __restrict__ query, const float* __restrict__ keyp,
    const float* __restrict__ value,
    const float* __restrict__ wofft, const float* __restrict__ wattnt,
    const float* __restrict__ b_off, const float* __restrict__ b_attn,
    const float* __restrict__ c_ws,
    float* __restrict__ off_ws, float* __restrict__ aw_ws,
    float* __restrict__ dotv_ws) {
  __shared__ __align__(16) unsigned short sAB[32768];  // 64 KB -> 2 blk/CU
  unsigned short* sA = sAB;
  unsigned short* sB = sAB + 16384;
  const int t = blockIdx.x;
  if (t < 64) {            // off = query @ WoffT^T + b_off   [1024][1024]
    mfma_tile128(query, wofft, b_off, nullptr, off_ws, 1024,
                 (t >> 3) * 128, (t & 7) * 128, sA, sB);
  } else if (t < 96) {     // aw = query @ WattnT^T + b_attn  [1024][512]
    const int u = t - 64;
    mfma_tile128(query, wattnt, b_attn, nullptr, aw_ws, 512,
                 (u >> 2) * 128, (u & 3) * 128, sA, sB);
  } else {                 // dotv = keyp @ value^T + c[m]    [1024][1024]
    const int u = t - 96;
    mfma_tile128(keyp, value, nullptr, c_ws, dotv_ws, 1024,
                 (u >> 3) * 128, (u & 7) * 128, sA, sB);
  }
}

// ---------------------------------------------------------------------------
// D3: per 2 queries: dotv rows as 32x32 images in LDS; per (q,d): softmax
// over 4 points, 4 bilinear samples; fused out = out1@W_o + b_o + query.
// (identical to the passing R3 kernel)
// ---------------------------------------------------------------------------
__global__ __launch_bounds__(256) void p3_kernel(
    const float* __restrict__ dotv, const float* __restrict__ off,
    const float* __restrict__ awr, const float* __restrict__ ref3d,
    const float* __restrict__ query, const float* __restrict__ W_o,
    const float* __restrict__ b_o, float* __restrict__ out) {
  __shared__ float img[2][NV];
  __shared__ float o1s[2][ND];

  const int tid = threadIdx.x;
  const int q0 = blockIdx.x * 2;

#pragma unroll
  for (int k = 0; k < 2; ++k) {
    int c = tid + k * 256;
    int qq = c >> 8, v4 = c & 255;
    *(float4*)(&img[qq][v4 * 4]) =
        *(const float4*)(dotv + (size_t)(q0 + qq) * NV + v4 * 4);
  }
  __syncthreads();

  {
    const int qq = tid >> 7;
    const int q = q0 + qq;
    const int d = tid & 127;
    const float* im = img[qq];
    const size_t qe = (size_t)q * ND + d;

    const float rx = ref3d[qe * 2 + 0];
    const float ry = ref3d[qe * 2 + 1];

    const float* awp = awr + (size_t)q * (ND * NP) + d * NP;
    const float a0 = awp[0], a1 = awp[1], a2 = awp[2], a3 = awp[3];
    const float mx = fmaxf(fmaxf(a0, a1), fmaxf(a2, a3));
    const float e0 = __expf(a0 - mx), e1 = __expf(a1 - mx),
                e2 = __expf(a2 - mx), e3 = __expf(a3 - mx);
    const float inv = 1.0f / (e0 + e1 + e2 + e3);
    const float wgt4[4] = {e0 * inv, e1 * inv, e2 * inv, e3 * inv};

    const float* op = off + (size_t)q * (ND * NP * 2) + d * (NP * 2);

    float acc = 0.0f;
#pragma unroll
    for (int p = 0; p < NP; ++p) {
      const float x = rx * (float)IMG_W + op[p * 2 + 0] - 0.5f;
      const float y = ry * (float)IMG_H + op[p * 2 + 1] - 0.5f;
      const float xf = floorf(x), yf = floorf(y);
      const int ix0 = (int)xf, iy0 = (int)yf;
      const float wx1 = x - xf, wy1 = y - yf;
      const float wx0 = 1.0f - wx1, wy0 = 1.0f - wy1;

      float s = 0.0f;
#pragma unroll
      for (int cy = 0; cy < 2; ++cy) {
#pragma unroll
        for (int cx = 0; cx < 2; ++cx) {
          const int ix = ix0 + cx, iy = iy0 + cy;
          const bool valid = (ix >= 0) & (ix < IMG_W) & (iy >= 0) & (iy < IMG_H);
          const int cix = min(max(ix, 0), IMG_W - 1);
          const int ciy = min(max(iy, 0), IMG_H - 1);
          const float wgt = (cx ? wx1 : wx0) * (cy ? wy1 : wy0);
          s += valid ? im[ciy * IMG_W + cix] * wgt : 0.0f;
        }
      }
      acc += wgt4[p] * s;
    }
    o1s[qq][d] = acc * (1.0f / 128.0f);
  }
  __syncthreads();

  {
    const int qq = tid >> 7;
    const int q = q0 + qq;
    const int n = tid & 127;
    float acc = b_o[n] + query[(size_t)q * 128 + n];
#pragma unroll 8
    for (int d = 0; d < 128; ++d)
      acc += o1s[qq][d] * W_o[(size_t)d * 128 + n];
    out[(size_t)q * 128 + n] = acc;
  }
}

// ---------------------------------------------------------------------------
extern "C" void kernel_launch(void* const* d_in, const int* in_sizes, int n_in,
                              void* d_out, int out_size, void* d_ws, size_t ws_size,
                              hipStream_t stream) {
  const float* query  = (const float*)d_in[0];
  const float* key    = (const float*)d_in[1];
  const float* value  = (const float*)d_in[2];
  const float* ref3d  = (const float*)d_in[3];
  // d_in[4] = spatial_shapes [[32,32]] (hardcoded)
  const float* W_off  = (const float*)d_in[5];
  const float* b_off  = (const float*)d_in[6];
  const float* W_attn = (const float*)d_in[7];
  const float* b_attn = (const float*)d_in[8];
  const float* W_v    = (const float*)d_in[9];
  const float* b_v    = (const float*)d_in[10];
  const float* W_o    = (const float*)d_in[11];
  const float* b_o    = (const float*)d_in[12];
  float* out = (float*)d_out;

  float* ws = (float*)d_ws;
  float* off_ws  = ws;                             // 1024*1024
  float* aw_ws   = off_ws + (size_t)NQ * 1024;     // 1024*512
  float* keyp_ws = aw_ws + (size_t)NQ * 512;       // 1024*128
  float* c_ws    = keyp_ws + (size_t)NQ * 128;     // 1024
  float* dotv_ws = c_ws + 1024;                    // 1024*1024
  float* wofft   = dotv_ws + (size_t)NQ * 1024;    // 1024*128 (W_off^T)
  float* wattnt  = wofft + (size_t)1024 * 128;     // 512*128  (W_attn^T)

  d1_kernel<<<57, 256, 0, stream>>>(key, W_v, b_v, W_off, W_attn,
                                    keyp_ws, c_ws, wofft, wattnt);
  d2_kernel<<<160, 256, 0, stream>>>(query, keyp_ws, value, wofft, wattnt,
                                     b_off, b_attn, c_ws,
                                     off_ws, aw_ws, dotv_ws);
  p3_kernel<<<512, 256, 0, stream>>>(dotv_ws, off_ws, aw_ws, ref3d, query,
                                     W_o, b_o, out);
}